// Round 2
// baseline (252.875 us; speedup 1.0000x reference)
//
#include <hip/hip_runtime.h>
#include <hip/hip_bf16.h>

typedef unsigned short u16;
typedef __attribute__((ext_vector_type(4))) float f32x4;
typedef __attribute__((ext_vector_type(8))) short short8;
typedef __attribute__((ext_vector_type(4))) short short4v;

__device__ __forceinline__ u16 f2b(float f) {
  unsigned u = __float_as_uint(f);
  u += 0x7fffu + ((u >> 16) & 1u);
  return (u16)(u >> 16);
}
__device__ __forceinline__ float b2f(u16 v) {
  return __uint_as_float(((unsigned)v) << 16);
}

// ---------------- GEMM: C[M][N] = A[M][K] @ B[N][K]^T ----------------
// A_BF16: A operand is bf16 (else f32, converted on load).
// OUT_F32: store f32 (for final output) else bf16.
template<bool A_BF16, bool OUT_F32>
__global__ __launch_bounds__(256) void gemm_bt(const void* __restrict__ Ap,
                                               const float* __restrict__ Bp,
                                               void* __restrict__ Cp,
                                               int M, int N, int K) {
  __shared__ u16 As[128][40];   // 80B rows: 16B aligned, conflict-light b128
  __shared__ u16 Bs[128][40];
  const int tid = threadIdx.x;
  const int lane = tid & 63;
  const int wv = tid >> 6;
  const int wr = wv >> 1, wc = wv & 1;
  const int bm = blockIdx.y * 128, bn = blockIdx.x * 128;
  const int ro = lane & 15, ko = (lane >> 4) * 8;
  f32x4 acc[4][4] = {};

  for (int kk = 0; kk < K; kk += 32) {
    short4v sa[4], sb[4];
    for (int i = 0; i < 4; ++i) {
      const int f = tid + 256 * i;
      const int row = f >> 3, c4 = (f & 7) * 4;
      if constexpr (A_BF16) {
        sa[i] = *reinterpret_cast<const short4v*>((const u16*)Ap + (size_t)(bm + row) * K + kk + c4);
      } else {
        f32x4 v = *reinterpret_cast<const f32x4*>((const float*)Ap + (size_t)(bm + row) * K + kk + c4);
        for (int j = 0; j < 4; ++j) sa[i][j] = (short)f2b(v[j]);
      }
      f32x4 w = *reinterpret_cast<const f32x4*>(Bp + (size_t)(bn + row) * K + kk + c4);
      for (int j = 0; j < 4; ++j) sb[i][j] = (short)f2b(w[j]);
    }
    __syncthreads();
    for (int i = 0; i < 4; ++i) {
      const int f = tid + 256 * i;
      const int row = f >> 3, c4 = (f & 7) * 4;
      *reinterpret_cast<short4v*>(&As[row][c4]) = sa[i];
      *reinterpret_cast<short4v*>(&Bs[row][c4]) = sb[i];
    }
    __syncthreads();
    short8 af[4], bfr[4];
    for (int m = 0; m < 4; ++m)
      af[m] = *reinterpret_cast<const short8*>(&As[wr * 64 + m * 16 + ro][ko]);
    for (int n = 0; n < 4; ++n)
      bfr[n] = *reinterpret_cast<const short8*>(&Bs[wc * 64 + n * 16 + ro][ko]);
    for (int m = 0; m < 4; ++m)
      for (int n = 0; n < 4; ++n)
        acc[m][n] = __builtin_amdgcn_mfma_f32_16x16x32_bf16(af[m], bfr[n], acc[m][n], 0, 0, 0);
  }
  for (int m = 0; m < 4; ++m)
    for (int n = 0; n < 4; ++n)
      for (int r = 0; r < 4; ++r) {
        const int row = bm + wr * 64 + m * 16 + (lane >> 4) * 4 + r;
        const int col = bn + wc * 64 + n * 16 + ro;
        if constexpr (OUT_F32) {
          ((float*)Cp)[(size_t)row * N + col] = acc[m][n][r];
        } else {
          ((u16*)Cp)[(size_t)row * N + col] = f2b(acc[m][n][r]);
        }
      }
}

// ---------------- RoPE + layout: qkv[4096][2304] -> Q,K [BH][S][64], V^T [BH][64][S] ----------------
__global__ __launch_bounds__(256) void rope_v_kernel(const u16* __restrict__ qkv,
                                                     const int* __restrict__ pos,
                                                     u16* __restrict__ Q,
                                                     u16* __restrict__ K,
                                                     u16* __restrict__ VT) {
  __shared__ u16 vs[64][72];
  const int tid = threadIdx.x;
  const int st = blockIdx.x * 64;            // token tile
  const int bh = blockIdx.y;                 // b*12+h
  const int b = bh / 12, h = bh % 12;

  // part 1: rotate q,k (exact reference indexing: pair i uses inv_freq[(2i) mod 32])
  for (int w = 0; w < 8; ++w) {
    const int idx = tid + 256 * w;           // 0..2047
    const int tok = idx >> 5;
    const int i = idx & 31;
    const int s = st + tok;
    const int p = pos[b * 2048 + s];
    const int mfreq = (2 * i) & 31;
    const float ang = (float)p * powf(10000.0f, -(float)mfreq / 32.0f);
    float sn, cs;
    __sincosf(ang, &sn, &cs);
    const size_t row = ((size_t)b * 2048 + s) * 2304;
    const int col = h * 64 + 2 * i;
    const float qe = b2f(qkv[row + col]),       qo = b2f(qkv[row + col + 1]);
    const float ke = b2f(qkv[row + 768 + col]), ko = b2f(qkv[row + 768 + col + 1]);
    const size_t qi = ((size_t)bh * 2048 + s) * 64 + 2 * i;
    Q[qi]     = f2b((qe * cs - qo * sn) * 0.125f);
    Q[qi + 1] = f2b((qo * cs + qe * sn) * 0.125f);
    K[qi]     = f2b(ke * cs - ko * sn);
    K[qi + 1] = f2b(ko * cs + ke * sn);
  }

  // part 2: V transpose via LDS (coalesced read + coalesced write)
  for (int w = 0; w < 2; ++w) {
    const int e = tid + 256 * w;             // 0..511
    const int tok = e >> 3, d0 = (e & 7) * 8;
    const size_t src = ((size_t)b * 2048 + st + tok) * 2304 + 1536 + h * 64 + d0;
    *reinterpret_cast<short8*>(&vs[tok][d0]) = *reinterpret_cast<const short8*>(qkv + src);
  }
  __syncthreads();
  for (int w = 0; w < 2; ++w) {
    const int e = tid + 256 * w;
    const int d = e >> 3, t0 = (e & 7) * 8;
    short8 u;
    for (int j = 0; j < 8; ++j) u[j] = (short)vs[t0 + j][d];
    const size_t dst = ((size_t)bh * 64 + d) * 2048 + st + t0;
    *reinterpret_cast<short8*>(VT + dst) = u;
  }
}

// ---------------- flash attention: 4 independent waves, 16 q-rows each ----------------
__global__ __launch_bounds__(256) void attn_kernel(const u16* __restrict__ Q,
                                                   const u16* __restrict__ K,
                                                   const u16* __restrict__ VT,
                                                   u16* __restrict__ ctx) {
  __shared__ u16 P_lds[4][16][72];
  const int tid = threadIdx.x;
  const int lane = tid & 63;
  const int wv = tid >> 6;
  const int bh = blockIdx.y;
  const int qt = blockIdx.x;
  const int qbase = qt * 64 + wv * 16;
  const int ro = lane & 15, qu = lane >> 4;

  const size_t qoff = ((size_t)bh * 2048 + qbase + ro) * 64 + qu * 8;
  short8 qf0 = *reinterpret_cast<const short8*>(Q + qoff);
  short8 qf1 = *reinterpret_cast<const short8*>(Q + qoff + 32);

  float m_r[4], l_r[4];
  f32x4 o[4] = {};
  for (int r = 0; r < 4; ++r) { m_r[r] = -__builtin_inff(); l_r[r] = 0.f; }

  for (int kv = 0; kv < 2048; kv += 64) {
    f32x4 s[4] = {};
    for (int g = 0; g < 4; ++g) {
      const size_t kb = ((size_t)bh * 2048 + kv + g * 16 + ro) * 64 + qu * 8;
      short8 kf0 = *reinterpret_cast<const short8*>(K + kb);
      short8 kf1 = *reinterpret_cast<const short8*>(K + kb + 32);
      s[g] = __builtin_amdgcn_mfma_f32_16x16x32_bf16(qf0, kf0, s[g], 0, 0, 0);
      s[g] = __builtin_amdgcn_mfma_f32_16x16x32_bf16(qf1, kf1, s[g], 0, 0, 0);
    }
    f32x4 scv;
    for (int r = 0; r < 4; ++r) {
      float tm = fmaxf(fmaxf(s[0][r], s[1][r]), fmaxf(s[2][r], s[3][r]));
      for (int off = 1; off < 16; off <<= 1) tm = fmaxf(tm, __shfl_xor(tm, off));
      const float nm = fmaxf(m_r[r], tm);
      const float sc = __expf(m_r[r] - nm);
      float p0 = __expf(s[0][r] - nm), p1 = __expf(s[1][r] - nm);
      float p2 = __expf(s[2][r] - nm), p3 = __expf(s[3][r] - nm);
      float ts = p0 + p1 + p2 + p3;
      for (int off = 1; off < 16; off <<= 1) ts += __shfl_xor(ts, off);
      m_r[r] = nm;
      l_r[r] = l_r[r] * sc + ts;
      scv[r] = sc;
      const int qrow = qu * 4 + r;
      P_lds[wv][qrow][ro]      = f2b(p0);
      P_lds[wv][qrow][16 + ro] = f2b(p1);
      P_lds[wv][qrow][32 + ro] = f2b(p2);
      P_lds[wv][qrow][48 + ro] = f2b(p3);
    }
    for (int g = 0; g < 4; ++g) o[g] *= scv;
    short8 pa0 = *reinterpret_cast<const short8*>(&P_lds[wv][ro][qu * 8]);
    short8 pa1 = *reinterpret_cast<const short8*>(&P_lds[wv][ro][32 + qu * 8]);
    for (int g = 0; g < 4; ++g) {
      const size_t vb = ((size_t)bh * 64 + g * 16 + ro) * 2048 + kv + qu * 8;
      short8 vf0 = *reinterpret_cast<const short8*>(VT + vb);
      short8 vf1 = *reinterpret_cast<const short8*>(VT + vb + 32);
      o[g] = __builtin_amdgcn_mfma_f32_16x16x32_bf16(pa0, vf0, o[g], 0, 0, 0);
      o[g] = __builtin_amdgcn_mfma_f32_16x16x32_bf16(pa1, vf1, o[g], 0, 0, 0);
    }
  }

  const int b = bh / 12, h = bh % 12;
  f32x4 inv;
  for (int r = 0; r < 4; ++r) inv[r] = 1.0f / l_r[r];
  for (int g = 0; g < 4; ++g)
    for (int r = 0; r < 4; ++r) {
      const int s_tok = qbase + qu * 4 + r;
      const size_t oi = ((size_t)b * 2048 + s_tok) * 768 + h * 64 + g * 16 + ro;
      ctx[oi] = f2b(o[g][r] * inv[r]);
    }
}

extern "C" void kernel_launch(void* const* d_in, const int* in_sizes, int n_in,
                              void* d_out, int out_size, void* d_ws, size_t ws_size,
                              hipStream_t stream) {
  const float* hidden = (const float*)d_in[0];
  const float* Wqkv   = (const float*)d_in[1];
  const float* Wo     = (const float*)d_in[2];
  const int*   pos    = (const int*)d_in[3];

  char* ws = (char*)d_ws;
  u16* qkv = (u16*)(ws);                        // 4096*2304*2 = 18874368
  u16* Qb  = (u16*)(ws + 18874368);             // 24*2048*64*2 = 6291456
  u16* Kb  = (u16*)(ws + 25165824);
  u16* VT  = (u16*)(ws + 31457280);
  u16* ctx = (u16*)(ws + 37748736);             // ends at 44040192

  gemm_bt<false, false><<<dim3(18, 32), 256, 0, stream>>>((const void*)hidden, Wqkv, qkv, 4096, 2304, 768);
  rope_v_kernel<<<dim3(32, 24), 256, 0, stream>>>(qkv, pos, Qb, Kb, VT);
  attn_kernel<<<dim3(32, 24), 256, 0, stream>>>(Qb, Kb, VT, ctx);
  gemm_bt<true, true><<<dim3(6, 32), 256, 0, stream>>>((const void*)ctx, Wo, (void*)d_out, 4096, 768, 768);
}